// Round 5
// baseline (420.913 us; speedup 1.0000x reference)
//
#include <hip/hip_runtime.h>

// GQA causal SDPA prefill, S=2048, H=32, G=8 kv-heads, D=128, fp32 in/out.
// Round 11: R8's latency-hiding schedule x R10's coalesced fragment layout.
// Prep emits K/V in exact per-lane MFMA fragment order
// (Kf/Vf[g][tile][frag][lane][8]) -> every sdpa K/V access is a fully
// coalesced global_load_dwordx4 from the XCD-pinned L2 (R10-verified,
// bank conflicts 0). Schedule: block = 256 thr = 4 waves = one (g,jj,h);
// waves split the jj's nt key-tiles 4-ways (wave s: kt = s, s+4, ...);
// un-shifted exp2 partials are additive -> one LDS atomicAdd combine.
// 2048 blocks heavy-first, g in low 3 bits (XCD pin). VGPR<=128 via
// __launch_bounds__(256,4) and 16.5 KB LDS -> 4 blocks/CU = 16 waves/CU
// = 4 waves/SIMD (2x R10's TLP; the R9/R10 bottleneck was exposed L2
// latency at 2 waves/SIMD). setprio dropped (homogeneous waves, m190).
// Compute math = R7/R10-verified, verbatim.

#define SEQ    2048
#define NH     32
#define NKV    8
#define DHEAD  128
#define QROW   (NH * DHEAD)    // 4096
#define KVROW  (NKV * DHEAD)   // 1024
#define SCALE  0.08838834764831845f
#define LOG2E  1.4426950408889634f
#define BN     64              // keys per tile
#define PSTR   136             // prep LDS stride (elems); 272 B keeps 16B align

typedef __attribute__((ext_vector_type(8))) short bf16x8;
typedef __attribute__((ext_vector_type(8))) unsigned short u16x8;
typedef __attribute__((ext_vector_type(16))) float f32x16;
typedef __attribute__((ext_vector_type(4))) unsigned int u32x4;

static __device__ __forceinline__ unsigned short f2bf(float f) {
  unsigned int u = __float_as_uint(f);
  return (unsigned short)((u + 0x7fffu + ((u >> 16) & 1u)) >> 16);
}

static __device__ __forceinline__ unsigned cvtpk_bf16(float lo, float hi) {
  unsigned r;
  asm("v_cvt_pk_bf16_f32 %0, %1, %2" : "=v"(r) : "v"(lo), "v"(hi));
  return r;
}

static __device__ __forceinline__ f32x16 zero16() {
  f32x16 z;
#pragma unroll
  for (int i = 0; i < 16; ++i) z[i] = 0.f;
  return z;
}

// ---- prep: fp32 [t][g][d] -> bf16 fragment-order Kf/Vf [g][t][frag][lane][8]
// K frag fk = kb*8+ks: elem(lane,j) = K[t*64 + kb*32 + (lane&31)][ks*16 + (lane>>5)*8 + j]
// V frag fv = ks2*4+nd: elem(lane,j) = V[t*64 + ks2*16 + (lane>>5)*8 + j][nd*32 + (lane&31)]
__global__ __launch_bounds__(256) void prep_frag_kernel(
    const float* __restrict__ K, const float* __restrict__ V,
    unsigned short* __restrict__ Kf, unsigned short* __restrict__ Vf) {
  __shared__ unsigned short Ks[64 * PSTR];
  __shared__ unsigned short Vs[64 * PSTR];
  const int tb  = blockIdx.x;          // tile 0..31
  const int g   = blockIdx.y;
  const int t0  = tb * 64;
  const int tid = threadIdx.x;
#pragma unroll
  for (int e = 0; e < 8; ++e) {
    int fi = e * 256 + tid;            // 0..2047 = 64 rows x 32 float4
    int r  = fi >> 5;
    int c4 = fi & 31;
    const float4 kv = *(const float4*)(K + (size_t)(t0 + r) * KVROW + g * DHEAD + c4 * 4);
    ushort4 kb4 = {f2bf(kv.x), f2bf(kv.y), f2bf(kv.z), f2bf(kv.w)};
    *(ushort4*)&Ks[r * PSTR + c4 * 4] = kb4;
    const float4 vv = *(const float4*)(V + (size_t)(t0 + r) * KVROW + g * DHEAD + c4 * 4);
    ushort4 vb4 = {f2bf(vv.x), f2bf(vv.y), f2bf(vv.z), f2bf(vv.w)};
    *(ushort4*)&Vs[r * PSTR + c4 * 4] = vb4;
  }
  __syncthreads();
  const size_t tbase = ((size_t)(g * 32 + tb)) << 13;   // 16 frags * 512 elems
#pragma unroll
  for (int q = 0; q < 4; ++q) {
    int slot = tid * 4 + q;            // 0..1023 = frag*64 + lane
    int fk   = slot >> 6;
    int lane = slot & 63;
    int l32v = lane & 31, hiv = lane >> 5;
    int row  = (fk >> 3) * 32 + l32v;
    int col  = (fk & 7) * 16 + hiv * 8;
    u16x8 o = *(const u16x8*)&Ks[row * PSTR + col];
    *(u16x8*)(Kf + tbase + slot * 8) = o;
  }
#pragma unroll
  for (int q = 0; q < 4; ++q) {
    int slot = tid * 4 + q;
    int fv   = slot >> 6;
    int lane = slot & 63;
    int l32v = lane & 31, hiv = lane >> 5;
    int d    = (fv & 3) * 32 + l32v;
    int key  = (fv >> 2) * 16 + hiv * 8;
    u16x8 o;
#pragma unroll
    for (int j = 0; j < 8; ++j) o[j] = Vs[(key + j) * PSTR + d];
    *(u16x8*)(Vf + tbase + slot * 8) = o;
  }
}

static __device__ __forceinline__ void load_qf(
    const float* __restrict__ Q, int q0, int h, int l32, int hi, bf16x8* qf) {
  const float* qp = Q + (size_t)(q0 + l32) * QROW + h * DHEAD + hi * 8;
#pragma unroll
  for (int ks = 0; ks < 8; ++ks) {
    const float4 a = *(const float4*)(qp + ks * 16);
    const float4 c = *(const float4*)(qp + ks * 16 + 4);
    bf16x8 v;
    v[0] = (short)f2bf(a.x * (SCALE * LOG2E));
    v[1] = (short)f2bf(a.y * (SCALE * LOG2E));
    v[2] = (short)f2bf(a.z * (SCALE * LOG2E));
    v[3] = (short)f2bf(a.w * (SCALE * LOG2E));
    v[4] = (short)f2bf(c.x * (SCALE * LOG2E));
    v[5] = (short)f2bf(c.y * (SCALE * LOG2E));
    v[6] = (short)f2bf(c.z * (SCALE * LOG2E));
    v[7] = (short)f2bf(c.w * (SCALE * LOG2E));
    qf[ks] = v;
  }
}

// Per k-step PV: transpose P^T (in regs) -> A-frag via cvt_pk + permlane32_swap
// (R7-verified), then 4 MFMAs against V frags loaded coalesced from global.
#define PV_KSTEP(PP, S, KS2)                                                     \
  do {                                                                           \
    unsigned y0 = cvtpk_bf16((PP)[(2 * (S)) * 4 + 0], (PP)[(2 * (S)) * 4 + 1]);  \
    unsigned z0 = cvtpk_bf16((PP)[(2 * (S)) * 4 + 2], (PP)[(2 * (S)) * 4 + 3]);  \
    unsigned y1 = cvtpk_bf16((PP)[(2 * (S) + 1) * 4 + 0], (PP)[(2 * (S) + 1) * 4 + 1]); \
    unsigned z1 = cvtpk_bf16((PP)[(2 * (S) + 1) * 4 + 2], (PP)[(2 * (S) + 1) * 4 + 3]); \
    asm("v_permlane32_swap_b32 %0, %1" : "+v"(y0), "+v"(y1));                    \
    asm("v_permlane32_swap_b32 %0, %1" : "+v"(z0), "+v"(z1));                    \
    u32x4 paw = (u32x4){y0, z0, y1, z1};                                         \
    bf16x8 pa = __builtin_bit_cast(bf16x8, paw);                                 \
    _Pragma("unroll")                                                            \
    for (int nd = 0; nd < 4; ++nd) {                                             \
      bf16x8 vf = *(const bf16x8*)(Vt + ((KS2) * 4 + nd) * 512 + lane * 8);      \
      oacc[nd] = __builtin_amdgcn_mfma_f32_32x32x16_bf16(pa, vf, oacc[nd], 0, 0, 0); \
    }                                                                            \
  } while (0)

static __device__ __forceinline__ void compute_tile_g(
    const unsigned short* __restrict__ Kt, const unsigned short* __restrict__ Vt,
    const bf16x8* qf, f32x16* oacc, float& lsum,
    int keyb, int q0, bool diag, int KB, int l32, int hi, int lane) {
  // ---- K frag loads (coalesced dwordx4) + swapped QK^T ----
  bf16x8 kf[8], kf2[8];
#pragma unroll
  for (int ks = 0; ks < 8; ++ks)
    kf[ks] = *(const bf16x8*)(Kt + ks * 512 + lane * 8);
  if (KB == 2) {
#pragma unroll
    for (int ks = 0; ks < 8; ++ks)
      kf2[ks] = *(const bf16x8*)(Kt + (8 + ks) * 512 + lane * 8);
  }
  f32x16 s0 = zero16();
  f32x16 s1 = zero16();
#pragma unroll
  for (int ks = 0; ks < 8; ++ks)
    s0 = __builtin_amdgcn_mfma_f32_32x32x16_bf16(kf[ks], qf[ks], s0, 0, 0, 0);
  if (KB == 2) {
#pragma unroll
    for (int ks = 0; ks < 8; ++ks)
      s1 = __builtin_amdgcn_mfma_f32_32x32x16_bf16(kf2[ks], qf[ks], s1, 0, 0, 0);
  }

  // ---- exp2 softmax (diag-specialized: non-diag tiles skip all mask VALU) ----
  f32x16 p0, p1;
  if (!diag) {   // KB == 2 always here
#pragma unroll
    for (int r = 0; r < 16; ++r) { float e = __builtin_amdgcn_exp2f(s0[r]); p0[r] = e; lsum += e; }
#pragma unroll
    for (int r = 0; r < 16; ++r) { float e = __builtin_amdgcn_exp2f(s1[r]); p1[r] = e; lsum += e; }
  } else {
#pragma unroll
    for (int r = 0; r < 16; ++r) {
      const int ko = (r & 3) + 8 * (r >> 2) + 4 * hi;
      float x = (keyb + ko > q0 + l32) ? -1e30f : s0[r];
      float e = __builtin_amdgcn_exp2f(x);
      p0[r] = e; lsum += e;
    }
    if (KB == 2) {
#pragma unroll
      for (int r = 0; r < 16; ++r) {
        const int ko = 32 + (r & 3) + 8 * (r >> 2) + 4 * hi;
        float x = (keyb + ko > q0 + l32) ? -1e30f : s1[r];
        float e = __builtin_amdgcn_exp2f(x);
        p1[r] = e; lsum += e;
      }
    }
  }

  // ---- O += P V ----
  PV_KSTEP(p0, 0, 0);
  PV_KSTEP(p0, 1, 1);
  if (KB == 2) {
    PV_KSTEP(p1, 0, 2);
    PV_KSTEP(p1, 1, 3);
  }
}

__global__ __launch_bounds__(256, 4) void sdpa_split4_kernel(
    const float* __restrict__ Q, float* __restrict__ O,
    const unsigned short* __restrict__ Kf, const unsigned short* __restrict__ Vf) {
  __shared__ float Obuf[32 * 128];   // 16 KB unnormalized O accumulator
  __shared__ float Lbuf[32];

  // b = ((jjcode*4 + hh) << 3) | g : g in low bits -> XCD-pinned KV;
  // jjcode ascending -> jj descending -> heavy blocks dispatched first.
  const int b      = blockIdx.x;
  const int g      = b & 7;
  const int hh     = (b >> 3) & 3;
  const int jjcode = b >> 5;                 // 0..63
  const int jj     = 63 - jjcode;
  const int q0     = jj * 32;
  const int nt     = (jj >> 1) + 1;          // 64-key tiles, 1..32
  const int tid  = threadIdx.x;
  const int s    = tid >> 6;                 // wave = key-chunk 0..3
  const int lane = tid & 63;
  const int l32  = lane & 31;
  const int hi   = lane >> 5;
  const int h    = g * 4 + hh;               // block's q-head

  // All 4 waves load the same 16 KB of Q -> L1 serves waves 1-3.
  bf16x8 qf[8];
  load_qf(Q, q0, h, l32, hi, qf);

  f32x16 oacc[4];
#pragma unroll
  for (int i = 0; i < 4; ++i) oacc[i] = zero16();
  float lsum = 0.f;

  // ---- key loop: wave-private tiles, no barriers ----
#pragma unroll 1
  for (int kt = s; kt < nt; kt += 4) {
    const bool diag = (kt == nt - 1);
    const int KB = (diag && !(jj & 1)) ? 1 : 2;  // even-jj diag: upper 32 keys fully masked
    const unsigned short* Kt = Kf + (((size_t)(g * 32 + kt)) << 13);
    const unsigned short* Vt = Vf + (((size_t)(g * 32 + kt)) << 13);
    compute_tile_g(Kt, Vt, qf, oacc, lsum, kt * BN, q0, diag, KB, l32, hi, lane);
  }

  // ---- combine: unnormalized partials are additive (un-shifted exp2) ----
  for (int i = tid; i < 32 * 128; i += 256) Obuf[i] = 0.f;
  if (tid < 32) Lbuf[tid] = 0.f;
  __syncthreads();
  {
    float tot = lsum + __shfl_xor(lsum, 32);
    if (hi == 0) atomicAdd(&Lbuf[l32], tot);
  }
#pragma unroll
  for (int nd = 0; nd < 4; ++nd)
#pragma unroll
    for (int r = 0; r < 16; ++r) {
      const int row = (r & 3) + 8 * (r >> 2) + 4 * hi;
      atomicAdd(&Obuf[row * 128 + nd * 32 + l32], oacc[nd][r]);
    }
  __syncthreads();

  // ---- normalize + store (thread -> 16 contiguous floats of one row) ----
  {
    const int row = tid >> 3;
    const int c0  = (tid & 7) * 16;
    const float inv = 1.f / Lbuf[row];
    float* orow = O + (size_t)(q0 + row) * QROW + h * DHEAD + c0;
    const float* src = &Obuf[row * 128 + c0];
#pragma unroll
    for (int j = 0; j < 4; ++j) {
      float4 v = *(const float4*)(src + j * 4);
      v.x *= inv; v.y *= inv; v.z *= inv; v.w *= inv;
      *(float4*)(orow + j * 4) = v;
    }
  }
}

extern "C" void kernel_launch(void* const* d_in, const int* in_sizes, int n_in,
                              void* d_out, int out_size, void* d_ws, size_t ws_size,
                              hipStream_t stream) {
  (void)in_sizes; (void)n_in; (void)out_size; (void)ws_size;
  const float* Q = (const float*)d_in[0];
  const float* K = (const float*)d_in[1];
  const float* V = (const float*)d_in[2];
  float* O = (float*)d_out;
  unsigned short* Kf = (unsigned short*)d_ws;                  // 4 MB
  unsigned short* Vf = Kf + (size_t)NKV * SEQ * DHEAD;         // 4 MB
  prep_frag_kernel<<<dim3(32, 8), 256, 0, stream>>>(K, V, Kf, Vf);
  sdpa_split4_kernel<<<2048, 256, 0, stream>>>(Q, O, Kf, Vf);
}

// Round 6
// 292.384 us; speedup vs baseline: 1.4396x; 1.4396x over previous
//
#include <hip/hip_runtime.h>

// GQA causal SDPA prefill, S=2048, H=32, G=8 kv-heads, D=128, fp32 in/out.
// Round 12: R11's schedule with a register-feasible build. R11's 356us was
// pure VGPR spill ( __launch_bounds__(256,4) = 128-reg cap vs ~150+ live;
// WRITE_SIZE 33->440 MB of scratch). Changes vs R11:
//   1. __launch_bounds__(256,3): ~170-reg cap -> no spill; occupancy set
//      by actual allocation (<=128 regs would give 4 waves/SIMD).
//   2. Tile processed as two sequential 32-key halves sharing one
//      kf[8]/s/p register set (was kf+kf2/s0+s1/p0+p1 all live) -> peak
//      live pressure drops ~64 regs. Same R7/R10-verified math.
// Schedule (unchanged from R11): prep emits K/V in per-lane MFMA fragment
// order -> all K/V loads are coalesced global_load_dwordx4 from the
// XCD-pinned L2. Block = 4 waves = one (g,jj,h); waves split the nt
// key-tiles 4-ways, no barriers in the key loop; un-shifted exp2 partials
// combined via LDS atomicAdd. 2048 blocks, heavy-first, g in low 3 bits.

#define SEQ    2048
#define NH     32
#define NKV    8
#define DHEAD  128
#define QROW   (NH * DHEAD)    // 4096
#define KVROW  (NKV * DHEAD)   // 1024
#define SCALE  0.08838834764831845f
#define LOG2E  1.4426950408889634f
#define BN     64              // keys per tile
#define PSTR   136             // prep LDS stride (elems); 272 B keeps 16B align

typedef __attribute__((ext_vector_type(8))) short bf16x8;
typedef __attribute__((ext_vector_type(8))) unsigned short u16x8;
typedef __attribute__((ext_vector_type(16))) float f32x16;
typedef __attribute__((ext_vector_type(4))) unsigned int u32x4;

static __device__ __forceinline__ unsigned short f2bf(float f) {
  unsigned int u = __float_as_uint(f);
  return (unsigned short)((u + 0x7fffu + ((u >> 16) & 1u)) >> 16);
}

static __device__ __forceinline__ unsigned cvtpk_bf16(float lo, float hi) {
  unsigned r;
  asm("v_cvt_pk_bf16_f32 %0, %1, %2" : "=v"(r) : "v"(lo), "v"(hi));
  return r;
}

static __device__ __forceinline__ f32x16 zero16() {
  f32x16 z;
#pragma unroll
  for (int i = 0; i < 16; ++i) z[i] = 0.f;
  return z;
}

// ---- prep: fp32 [t][g][d] -> bf16 fragment-order Kf/Vf [g][t][frag][lane][8]
// K frag fk = kb*8+ks: elem(lane,j) = K[t*64 + kb*32 + (lane&31)][ks*16 + (lane>>5)*8 + j]
// V frag fv = ks2*4+nd: elem(lane,j) = V[t*64 + ks2*16 + (lane>>5)*8 + j][nd*32 + (lane&31)]
__global__ __launch_bounds__(256) void prep_frag_kernel(
    const float* __restrict__ K, const float* __restrict__ V,
    unsigned short* __restrict__ Kf, unsigned short* __restrict__ Vf) {
  __shared__ unsigned short Ks[64 * PSTR];
  __shared__ unsigned short Vs[64 * PSTR];
  const int tb  = blockIdx.x;          // tile 0..31
  const int g   = blockIdx.y;
  const int t0  = tb * 64;
  const int tid = threadIdx.x;
#pragma unroll
  for (int e = 0; e < 8; ++e) {
    int fi = e * 256 + tid;            // 0..2047 = 64 rows x 32 float4
    int r  = fi >> 5;
    int c4 = fi & 31;
    const float4 kv = *(const float4*)(K + (size_t)(t0 + r) * KVROW + g * DHEAD + c4 * 4);
    ushort4 kb4 = {f2bf(kv.x), f2bf(kv.y), f2bf(kv.z), f2bf(kv.w)};
    *(ushort4*)&Ks[r * PSTR + c4 * 4] = kb4;
    const float4 vv = *(const float4*)(V + (size_t)(t0 + r) * KVROW + g * DHEAD + c4 * 4);
    ushort4 vb4 = {f2bf(vv.x), f2bf(vv.y), f2bf(vv.z), f2bf(vv.w)};
    *(ushort4*)&Vs[r * PSTR + c4 * 4] = vb4;
  }
  __syncthreads();
  const size_t tbase = ((size_t)(g * 32 + tb)) << 13;   // 16 frags * 512 elems
#pragma unroll
  for (int q = 0; q < 4; ++q) {
    int slot = tid * 4 + q;            // 0..1023 = frag*64 + lane
    int fk   = slot >> 6;
    int lane = slot & 63;
    int l32v = lane & 31, hiv = lane >> 5;
    int row  = (fk >> 3) * 32 + l32v;
    int col  = (fk & 7) * 16 + hiv * 8;
    u16x8 o = *(const u16x8*)&Ks[row * PSTR + col];
    *(u16x8*)(Kf + tbase + slot * 8) = o;
  }
#pragma unroll
  for (int q = 0; q < 4; ++q) {
    int slot = tid * 4 + q;
    int fv   = slot >> 6;
    int lane = slot & 63;
    int l32v = lane & 31, hiv = lane >> 5;
    int d    = (fv & 3) * 32 + l32v;
    int key  = (fv >> 2) * 16 + hiv * 8;
    u16x8 o;
#pragma unroll
    for (int j = 0; j < 8; ++j) o[j] = Vs[(key + j) * PSTR + d];
    *(u16x8*)(Vf + tbase + slot * 8) = o;
  }
}

static __device__ __forceinline__ void load_qf(
    const float* __restrict__ Q, int q0, int h, int l32, int hi, bf16x8* qf) {
  const float* qp = Q + (size_t)(q0 + l32) * QROW + h * DHEAD + hi * 8;
#pragma unroll
  for (int ks = 0; ks < 8; ++ks) {
    const float4 a = *(const float4*)(qp + ks * 16);
    const float4 c = *(const float4*)(qp + ks * 16 + 4);
    bf16x8 v;
    v[0] = (short)f2bf(a.x * (SCALE * LOG2E));
    v[1] = (short)f2bf(a.y * (SCALE * LOG2E));
    v[2] = (short)f2bf(a.z * (SCALE * LOG2E));
    v[3] = (short)f2bf(a.w * (SCALE * LOG2E));
    v[4] = (short)f2bf(c.x * (SCALE * LOG2E));
    v[5] = (short)f2bf(c.y * (SCALE * LOG2E));
    v[6] = (short)f2bf(c.z * (SCALE * LOG2E));
    v[7] = (short)f2bf(c.w * (SCALE * LOG2E));
    qf[ks] = v;
  }
}

// Per k-step PV: transpose P^T (in regs) -> A-frag via cvt_pk + permlane32_swap
// (R7-verified), then 4 MFMAs against V frags loaded coalesced from global.
#define PV_KSTEP(PP, S, KS2)                                                     \
  do {                                                                           \
    unsigned y0 = cvtpk_bf16((PP)[(2 * (S)) * 4 + 0], (PP)[(2 * (S)) * 4 + 1]);  \
    unsigned z0 = cvtpk_bf16((PP)[(2 * (S)) * 4 + 2], (PP)[(2 * (S)) * 4 + 3]);  \
    unsigned y1 = cvtpk_bf16((PP)[(2 * (S) + 1) * 4 + 0], (PP)[(2 * (S) + 1) * 4 + 1]); \
    unsigned z1 = cvtpk_bf16((PP)[(2 * (S) + 1) * 4 + 2], (PP)[(2 * (S) + 1) * 4 + 3]); \
    asm("v_permlane32_swap_b32 %0, %1" : "+v"(y0), "+v"(y1));                    \
    asm("v_permlane32_swap_b32 %0, %1" : "+v"(z0), "+v"(z1));                    \
    u32x4 paw = (u32x4){y0, z0, y1, z1};                                         \
    bf16x8 pa = __builtin_bit_cast(bf16x8, paw);                                 \
    _Pragma("unroll")                                                            \
    for (int nd = 0; nd < 4; ++nd) {                                             \
      bf16x8 vf = *(const bf16x8*)(Vt + ((KS2) * 4 + nd) * 512 + lane * 8);      \
      oacc[nd] = __builtin_amdgcn_mfma_f32_32x32x16_bf16(pa, vf, oacc[nd], 0, 0, 0); \
    }                                                                            \
  } while (0)

// One 32-key half: load 8 K-frags, QK^T, mask+exp2, PV. Only one kf/s/p
// register set live at a time (R12 pressure fix).
static __device__ __forceinline__ void compute_half(
    const unsigned short* __restrict__ Kt, const unsigned short* __restrict__ Vt,
    const bf16x8* qf, f32x16* oacc, float& lsum,
    int keyb, int q0, bool diag, int kb, int l32, int hi, int lane) {
  bf16x8 kf[8];
#pragma unroll
  for (int ks = 0; ks < 8; ++ks)
    kf[ks] = *(const bf16x8*)(Kt + (kb * 8 + ks) * 512 + lane * 8);
  f32x16 s = zero16();
#pragma unroll
  for (int ks = 0; ks < 8; ++ks)
    s = __builtin_amdgcn_mfma_f32_32x32x16_bf16(kf[ks], qf[ks], s, 0, 0, 0);

  f32x16 p;
  if (!diag) {
#pragma unroll
    for (int r = 0; r < 16; ++r) {
      float e = __builtin_amdgcn_exp2f(s[r]);
      p[r] = e; lsum += e;
    }
  } else {
#pragma unroll
    for (int r = 0; r < 16; ++r) {
      const int ko = (r & 3) + 8 * (r >> 2) + 4 * hi;
      float x = (keyb + ko > q0 + l32) ? -1e30f : s[r];
      float e = __builtin_amdgcn_exp2f(x);
      p[r] = e; lsum += e;
    }
  }

  PV_KSTEP(p, 0, kb * 2 + 0);
  PV_KSTEP(p, 1, kb * 2 + 1);
}

__global__ __launch_bounds__(256, 3) void sdpa_split4_kernel(
    const float* __restrict__ Q, float* __restrict__ O,
    const unsigned short* __restrict__ Kf, const unsigned short* __restrict__ Vf) {
  __shared__ float Obuf[32 * 128];   // 16 KB unnormalized O accumulator
  __shared__ float Lbuf[32];

  // b = ((jjcode*4 + hh) << 3) | g : g in low bits -> XCD-pinned KV;
  // jjcode ascending -> jj descending -> heavy blocks dispatched first.
  const int b      = blockIdx.x;
  const int g      = b & 7;
  const int hh     = (b >> 3) & 3;
  const int jjcode = b >> 5;                 // 0..63
  const int jj     = 63 - jjcode;
  const int q0     = jj * 32;
  const int nt     = (jj >> 1) + 1;          // 64-key tiles, 1..32
  const int tid  = threadIdx.x;
  const int s    = tid >> 6;                 // wave = key-chunk 0..3
  const int lane = tid & 63;
  const int l32  = lane & 31;
  const int hi   = lane >> 5;
  const int h    = g * 4 + hh;               // block's q-head

  // All 4 waves load the same 16 KB of Q -> L1 serves waves 1-3.
  bf16x8 qf[8];
  load_qf(Q, q0, h, l32, hi, qf);

  f32x16 oacc[4];
#pragma unroll
  for (int i = 0; i < 4; ++i) oacc[i] = zero16();
  float lsum = 0.f;

  // ---- key loop: wave-private tiles, no barriers ----
#pragma unroll 1
  for (int kt = s; kt < nt; kt += 4) {
    const bool diag = (kt == nt - 1);
    const int KB = (diag && !(jj & 1)) ? 1 : 2;  // even-jj diag: upper 32 keys fully masked
    const unsigned short* Kt = Kf + (((size_t)(g * 32 + kt)) << 13);
    const unsigned short* Vt = Vf + (((size_t)(g * 32 + kt)) << 13);
    compute_half(Kt, Vt, qf, oacc, lsum, kt * BN, q0, diag, 0, l32, hi, lane);
    if (KB == 2)
      compute_half(Kt, Vt, qf, oacc, lsum, kt * BN + 32, q0, diag, 1, l32, hi, lane);
  }

  // ---- combine: unnormalized partials are additive (un-shifted exp2) ----
  for (int i = tid; i < 32 * 128; i += 256) Obuf[i] = 0.f;
  if (tid < 32) Lbuf[tid] = 0.f;
  __syncthreads();
  {
    float tot = lsum + __shfl_xor(lsum, 32);
    if (hi == 0) atomicAdd(&Lbuf[l32], tot);
  }
#pragma unroll
  for (int nd = 0; nd < 4; ++nd)
#pragma unroll
    for (int r = 0; r < 16; ++r) {
      const int row = (r & 3) + 8 * (r >> 2) + 4 * hi;
      atomicAdd(&Obuf[row * 128 + nd * 32 + l32], oacc[nd][r]);
    }
  __syncthreads();

  // ---- normalize + store (thread -> 16 contiguous floats of one row) ----
  {
    const int row = tid >> 3;
    const int c0  = (tid & 7) * 16;
    const float inv = 1.f / Lbuf[row];
    float* orow = O + (size_t)(q0 + row) * QROW + h * DHEAD + c0;
    const float* src = &Obuf[row * 128 + c0];
#pragma unroll
    for (int j = 0; j < 4; ++j) {
      float4 v = *(const float4*)(src + j * 4);
      v.x *= inv; v.y *= inv; v.z *= inv; v.w *= inv;
      *(float4*)(orow + j * 4) = v;
    }
  }
}

extern "C" void kernel_launch(void* const* d_in, const int* in_sizes, int n_in,
                              void* d_out, int out_size, void* d_ws, size_t ws_size,
                              hipStream_t stream) {
  (void)in_sizes; (void)n_in; (void)out_size; (void)ws_size;
  const float* Q = (const float*)d_in[0];
  const float* K = (const float*)d_in[1];
  const float* V = (const float*)d_in[2];
  float* O = (float*)d_out;
  unsigned short* Kf = (unsigned short*)d_ws;                  // 4 MB
  unsigned short* Vf = Kf + (size_t)NKV * SEQ * DHEAD;         // 4 MB
  prep_frag_kernel<<<dim3(32, 8), 256, 0, stream>>>(K, V, Kf, Vf);
  sdpa_split4_kernel<<<2048, 256, 0, stream>>>(Q, O, Kf, Vf);
}

// Round 7
// 139.569 us; speedup vs baseline: 3.0158x; 2.0949x over previous
//
#include <hip/hip_runtime.h>

// GQA causal SDPA prefill, S=2048, H=32, G=8 kv-heads, D=128, fp32 in/out.
// Round 13: R10's 256-block pair schedule (verified, 73us) with the
// per-visit wait-structure collapsed. Evidence: all 256-block tile-local
// designs (R6/R7/R9/R10) sit at ~70us = ~5.3k cyc per tile-visit-slot,
// while issue cost is only ~1k cyc -> ~5 serialized wait points x ~700cyc
// loaded-L2 latency at 2 waves/SIMD. Change: compute_tile front-loads ALL
// fragment loads (16 K-frags, then 8 V-frags(h0)) before any MFMA, issues
// V-frags(h1) between the QK halves. Loads return in order -> single
// exposed K-wait per visit; V latency hides under QK MFMAs + softmax.
// Peak regs ~224 (staggered lifetimes) under the (512,2) 256-reg cap --
// NO spill (R11 lesson: check WRITE_SIZE stays ~33 MB).
// Everything else (prep frag layout, pair schedule, jj_l store, jj_h
// LDS merge, epilogue) is R10-verbatim.

#define SEQ    2048
#define NH     32
#define NKV    8
#define DHEAD  128
#define QROW   (NH * DHEAD)    // 4096
#define KVROW  (NKV * DHEAD)   // 1024
#define SCALE  0.08838834764831845f
#define LOG2E  1.4426950408889634f
#define BN     64              // keys per tile
#define PSTR   136             // prep LDS stride (elems); 272 B keeps 16B align

typedef __attribute__((ext_vector_type(8))) short bf16x8;
typedef __attribute__((ext_vector_type(8))) unsigned short u16x8;
typedef __attribute__((ext_vector_type(16))) float f32x16;
typedef __attribute__((ext_vector_type(4))) unsigned int u32x4;

static __device__ __forceinline__ unsigned short f2bf(float f) {
  unsigned int u = __float_as_uint(f);
  return (unsigned short)((u + 0x7fffu + ((u >> 16) & 1u)) >> 16);
}

static __device__ __forceinline__ unsigned cvtpk_bf16(float lo, float hi) {
  unsigned r;
  asm("v_cvt_pk_bf16_f32 %0, %1, %2" : "=v"(r) : "v"(lo), "v"(hi));
  return r;
}

static __device__ __forceinline__ f32x16 zero16() {
  f32x16 z;
#pragma unroll
  for (int i = 0; i < 16; ++i) z[i] = 0.f;
  return z;
}

// ---- prep: fp32 [t][g][d] -> bf16 fragment-order Kf/Vf [g][t][frag][lane][8]
// K frag fk = kb*8+ks: elem(lane,j) = K[t*64 + kb*32 + (lane&31)][ks*16 + (lane>>5)*8 + j]
// V frag fv = ks2*4+nd: elem(lane,j) = V[t*64 + ks2*16 + (lane>>5)*8 + j][nd*32 + (lane&31)]
__global__ __launch_bounds__(256) void prep_frag_kernel(
    const float* __restrict__ K, const float* __restrict__ V,
    unsigned short* __restrict__ Kf, unsigned short* __restrict__ Vf) {
  __shared__ unsigned short Ks[64 * PSTR];
  __shared__ unsigned short Vs[64 * PSTR];
  const int tb  = blockIdx.x;          // tile 0..31
  const int g   = blockIdx.y;
  const int t0  = tb * 64;
  const int tid = threadIdx.x;
#pragma unroll
  for (int e = 0; e < 8; ++e) {
    int fi = e * 256 + tid;            // 0..2047 = 64 rows x 32 float4
    int r  = fi >> 5;
    int c4 = fi & 31;
    const float4 kv = *(const float4*)(K + (size_t)(t0 + r) * KVROW + g * DHEAD + c4 * 4);
    ushort4 kb4 = {f2bf(kv.x), f2bf(kv.y), f2bf(kv.z), f2bf(kv.w)};
    *(ushort4*)&Ks[r * PSTR + c4 * 4] = kb4;
    const float4 vv = *(const float4*)(V + (size_t)(t0 + r) * KVROW + g * DHEAD + c4 * 4);
    ushort4 vb4 = {f2bf(vv.x), f2bf(vv.y), f2bf(vv.z), f2bf(vv.w)};
    *(ushort4*)&Vs[r * PSTR + c4 * 4] = vb4;
  }
  __syncthreads();
  const size_t tbase = ((size_t)(g * 32 + tb)) << 13;   // 16 frags * 512 elems
#pragma unroll
  for (int q = 0; q < 4; ++q) {
    int slot = tid * 4 + q;            // 0..1023 = frag*64 + lane
    int fk   = slot >> 6;
    int lane = slot & 63;
    int l32v = lane & 31, hiv = lane >> 5;
    int row  = (fk >> 3) * 32 + l32v;
    int col  = (fk & 7) * 16 + hiv * 8;
    u16x8 o = *(const u16x8*)&Ks[row * PSTR + col];
    *(u16x8*)(Kf + tbase + slot * 8) = o;
  }
#pragma unroll
  for (int q = 0; q < 4; ++q) {
    int slot = tid * 4 + q;
    int fv   = slot >> 6;
    int lane = slot & 63;
    int l32v = lane & 31, hiv = lane >> 5;
    int d    = (fv & 3) * 32 + l32v;
    int key  = (fv >> 2) * 16 + hiv * 8;
    u16x8 o;
#pragma unroll
    for (int j = 0; j < 8; ++j) o[j] = Vs[(key + j) * PSTR + d];
    *(u16x8*)(Vf + tbase + slot * 8) = o;
  }
}

static __device__ __forceinline__ void load_qf(
    const float* __restrict__ Q, int q0, int h, int l32, int hi, bf16x8* qf) {
  const float* qp = Q + (size_t)(q0 + l32) * QROW + h * DHEAD + hi * 8;
#pragma unroll
  for (int ks = 0; ks < 8; ++ks) {
    const float4 a = *(const float4*)(qp + ks * 16);
    const float4 c = *(const float4*)(qp + ks * 16 + 4);
    bf16x8 v;
    v[0] = (short)f2bf(a.x * (SCALE * LOG2E));
    v[1] = (short)f2bf(a.y * (SCALE * LOG2E));
    v[2] = (short)f2bf(a.z * (SCALE * LOG2E));
    v[3] = (short)f2bf(a.w * (SCALE * LOG2E));
    v[4] = (short)f2bf(c.x * (SCALE * LOG2E));
    v[5] = (short)f2bf(c.y * (SCALE * LOG2E));
    v[6] = (short)f2bf(c.z * (SCALE * LOG2E));
    v[7] = (short)f2bf(c.w * (SCALE * LOG2E));
    qf[ks] = v;
  }
}

// Per k-step PV: transpose P^T (in regs) -> A-frag via cvt_pk + permlane32_swap
// (R7-verified), then 4 MFMAs against preloaded V frag registers.
#define PV_KSTEP(PP, S, VF)                                                      \
  do {                                                                           \
    unsigned y0 = cvtpk_bf16((PP)[(2 * (S)) * 4 + 0], (PP)[(2 * (S)) * 4 + 1]);  \
    unsigned z0 = cvtpk_bf16((PP)[(2 * (S)) * 4 + 2], (PP)[(2 * (S)) * 4 + 3]);  \
    unsigned y1 = cvtpk_bf16((PP)[(2 * (S) + 1) * 4 + 0], (PP)[(2 * (S) + 1) * 4 + 1]); \
    unsigned z1 = cvtpk_bf16((PP)[(2 * (S) + 1) * 4 + 2], (PP)[(2 * (S) + 1) * 4 + 3]); \
    asm("v_permlane32_swap_b32 %0, %1" : "+v"(y0), "+v"(y1));                    \
    asm("v_permlane32_swap_b32 %0, %1" : "+v"(z0), "+v"(z1));                    \
    u32x4 paw = (u32x4){y0, z0, y1, z1};                                         \
    bf16x8 pa = __builtin_bit_cast(bf16x8, paw);                                 \
    _Pragma("unroll")                                                            \
    for (int nd = 0; nd < 4; ++nd)                                               \
      oacc[nd] = __builtin_amdgcn_mfma_f32_32x32x16_bf16(pa, (VF)[(S) * 4 + nd], \
                                                         oacc[nd], 0, 0, 0);     \
  } while (0)

// One tile-visit, single-wait-front-loaded:
//   issue 16 K loads + 8 V(h0) loads -> QK h0 -> issue 8 V(h1) -> QK h1
//   -> softmax both -> PV both. Only the K wait is exposed; V returns
//   under QK MFMAs + softmax VALU (loads complete in issue order).
static __device__ __forceinline__ void compute_tile_p(
    const unsigned short* __restrict__ Kt, const unsigned short* __restrict__ Vt,
    const bf16x8* qf, f32x16* oacc, float& lsum,
    int keyb, int q0, bool diag, int KB, int l32, int hi, int lane) {
  const unsigned short* kp = Kt + lane * 8;
  const unsigned short* vp = Vt + lane * 8;

  bf16x8 kf0[8], kf1[8], vfa[8], vfb[8];
#pragma unroll
  for (int ks = 0; ks < 8; ++ks)
    kf0[ks] = *(const bf16x8*)(kp + ks * 512);
  if (KB == 2) {
#pragma unroll
    for (int ks = 0; ks < 8; ++ks)
      kf1[ks] = *(const bf16x8*)(kp + (8 + ks) * 512);
  }
#pragma unroll
  for (int j = 0; j < 8; ++j)
    vfa[j] = *(const bf16x8*)(vp + j * 512);

  // ---- QK h0 (the only exposed wait) ----
  f32x16 s0 = zero16();
#pragma unroll
  for (int ks = 0; ks < 8; ++ks)
    s0 = __builtin_amdgcn_mfma_f32_32x32x16_bf16(kf0[ks], qf[ks], s0, 0, 0, 0);

  // ---- V h1 issue + QK h1 ----
  f32x16 s1;
  if (KB == 2) {
#pragma unroll
    for (int j = 0; j < 8; ++j)
      vfb[j] = *(const bf16x8*)(vp + (8 + j) * 512);
    s1 = zero16();
#pragma unroll
    for (int ks = 0; ks < 8; ++ks)
      s1 = __builtin_amdgcn_mfma_f32_32x32x16_bf16(kf1[ks], qf[ks], s1, 0, 0, 0);
  }

  // ---- exp2 softmax (diag-specialized) ----
  f32x16 p0, p1;
  if (!diag) {   // KB == 2 always here
#pragma unroll
    for (int r = 0; r < 16; ++r) { float e = __builtin_amdgcn_exp2f(s0[r]); p0[r] = e; lsum += e; }
#pragma unroll
    for (int r = 0; r < 16; ++r) { float e = __builtin_amdgcn_exp2f(s1[r]); p1[r] = e; lsum += e; }
  } else {
#pragma unroll
    for (int r = 0; r < 16; ++r) {
      const int ko = (r & 3) + 8 * (r >> 2) + 4 * hi;
      float x = (keyb + ko > q0 + l32) ? -1e30f : s0[r];
      float e = __builtin_amdgcn_exp2f(x);
      p0[r] = e; lsum += e;
    }
    if (KB == 2) {
#pragma unroll
      for (int r = 0; r < 16; ++r) {
        const int ko = 32 + (r & 3) + 8 * (r >> 2) + 4 * hi;
        float x = (keyb + ko > q0 + l32) ? -1e30f : s1[r];
        float e = __builtin_amdgcn_exp2f(x);
        p1[r] = e; lsum += e;
      }
    }
  }

  // ---- O += P V (V already in registers) ----
  PV_KSTEP(p0, 0, vfa);
  PV_KSTEP(p0, 1, vfa);
  if (KB == 2) {
    PV_KSTEP(p1, 0, vfb);
    PV_KSTEP(p1, 1, vfb);
  }
}

__global__ __launch_bounds__(512, 2) void sdpa_frag_kernel(
    const float* __restrict__ Q, float* __restrict__ O,
    const unsigned short* __restrict__ Kf, const unsigned short* __restrict__ Vf) {
  __shared__ float Obuf[4][32 * 128];   // 64 KB jj_h merge buffer
  __shared__ float Lb[4][32];

  const int b    = blockIdx.x;
  const int g    = b & 7;               // XCD-pinned KV
  const int p    = b >> 3;              // 0..31 pair index
  const int nt_l = (p + 2) >> 1;        // 1..16
  const int nt_h = 33 - nt_l;           // 17..32
  const int jj_h = 63 - p;
  const int jj_l = p;
  const int tid  = threadIdx.x;
  const int w    = tid >> 6;
  const int lane = tid & 63;
  const int l32  = lane & 31;
  const int hi   = lane >> 5;
  const int grp  = w >> 2;              // 0 = jj_h tiles 0..16; 1 = jj_l then jj_h tail
  const int wg   = w & 3;
  const int h    = g * 4 + wg;

  int q0 = (grp ? jj_l : jj_h) * 32;

  bf16x8 qf[8];
  load_qf(Q, q0, h, l32, hi, qf);

  f32x16 oacc[4];
#pragma unroll
  for (int i = 0; i < 4; ++i) oacc[i] = zero16();
  float lsum = 0.f;

  const int niters = grp ? 16 : 17;
#pragma unroll 1
  for (int i = 0; i < niters; ++i) {
    int t, jjc;
    bool diag;
    if (grp == 0)      { t = i;                jjc = jj_h; diag = (nt_h == 17) && (i == 16); }
    else if (i < nt_l) { t = i;                jjc = jj_l; diag = (i == nt_l - 1); }
    else               { t = 17 + i - nt_l;    jjc = jj_h; diag = (i == 15); }
    const int KB = (diag && !(jjc & 1)) ? 1 : 2;
    const unsigned short* Kt = Kf + (((size_t)(g * 32 + t)) << 13);
    const unsigned short* Vt = Vf + (((size_t)(g * 32 + t)) << 13);
    compute_tile_p(Kt, Vt, qf, oacc, lsum, t * BN, q0, diag, KB, l32, hi, lane);

    if (grp == 1 && i == nt_l - 1) {
      // store jj_l output wave-locally, reset, switch to jj_h tail
      float tot = lsum + __shfl_xor(lsum, 32);
      float inv = 1.f / tot;
#pragma unroll
      for (int nd = 0; nd < 4; ++nd)
#pragma unroll
        for (int r = 0; r < 16; ++r) {
          const int row = (r & 3) + 8 * (r >> 2) + 4 * hi;
          O[(size_t)(q0 + row) * QROW + h * DHEAD + nd * 32 + l32] =
              oacc[nd][r] * __shfl(inv, row);
        }
#pragma unroll
      for (int i2 = 0; i2 < 4; ++i2) oacc[i2] = zero16();
      lsum = 0.f;
      q0 = jj_h * 32;
      load_qf(Q, q0, h, l32, hi, qf);
    }
  }

  // ---- merge jj_h: B dumps unnormalized partials to LDS, A adds + stores ----
  float tot = lsum + __shfl_xor(lsum, 32);
  if (grp == 1) {
    if (hi == 0) Lb[wg][l32] = tot;
    float* ob = &Obuf[wg][0];
#pragma unroll
    for (int nd = 0; nd < 4; ++nd)
#pragma unroll
      for (int r = 0; r < 16; ++r) {
        const int row = (r & 3) + 8 * (r >> 2) + 4 * hi;
        ob[row * 128 + nd * 32 + l32] = oacc[nd][r];
      }
  }
  __syncthreads();
  if (grp == 0) {
    tot += Lb[wg][l32];
    float inv = 1.f / tot;
    const float* ob = &Obuf[wg][0];
#pragma unroll
    for (int nd = 0; nd < 4; ++nd)
#pragma unroll
      for (int r = 0; r < 16; ++r) {
        const int row = (r & 3) + 8 * (r >> 2) + 4 * hi;
        float val = oacc[nd][r] + ob[row * 128 + nd * 32 + l32];
        O[(size_t)(q0 + row) * QROW + h * DHEAD + nd * 32 + l32] =
            val * __shfl(inv, row);
      }
  }
}

extern "C" void kernel_launch(void* const* d_in, const int* in_sizes, int n_in,
                              void* d_out, int out_size, void* d_ws, size_t ws_size,
                              hipStream_t stream) {
  (void)in_sizes; (void)n_in; (void)out_size; (void)ws_size;
  const float* Q = (const float*)d_in[0];
  const float* K = (const float*)d_in[1];
  const float* V = (const float*)d_in[2];
  float* O = (float*)d_out;
  unsigned short* Kf = (unsigned short*)d_ws;                  // 4 MB
  unsigned short* Vf = Kf + (size_t)NKV * SEQ * DHEAD;         // 4 MB
  prep_frag_kernel<<<dim3(32, 8), 256, 0, stream>>>(K, V, Kf, Vf);
  sdpa_frag_kernel<<<256, 512, 0, stream>>>(Q, O, Kf, Vf);
}